// Round 4
// baseline (54.655 us; speedup 1.0000x reference)
//
#include <hip/hip_runtime.h>

// Fredkin6Layer: out[b, 3g+c] = sum_p softmax(wgts[g])[p] * signals(c, perm p)
// over a = x[b, (3g+1 .. 3g+3) % DIN].  Algebraically reduced to 9 coefs/gate.

constexpr int DIN  = 4096;
constexpr int NG   = 2048;   // gates
constexpr int GPB  = 1024;   // gates per block tile
constexpr int GPT  = 4;      // gates per thread
constexpr int RT   = 4;      // batch rows per block
constexpr int SEG  = 3076;   // floats of x staged per row (covers 12*255+15)
constexpr int SEG4 = 769;    // float4 per row

__global__ __launch_bounds__(256, 3) void fredkin_kernel(
    const float* __restrict__ x,
    const float* __restrict__ wgts,
    float* __restrict__ out)
{
    __shared__ float sx[RT][SEG];

    const int tid  = threadIdx.x;
    const int gt   = blockIdx.x & 1;     // 2 gate tiles
    const int rt   = blockIdx.x >> 1;    // 1024 row tiles
    const int g0   = gt * GPB;
    const int base = 3 * g0;             // 0 or 3072 (mult. of 4)
    const int b0   = rt * RT;

    // ---- per-thread coefficients for its 4 gates (softmax in registers) ----
    float cw[GPT][3], dl[GPT][3], qc[GPT][3];
    {
        const float4* wp =
            reinterpret_cast<const float4*>(wgts + (size_t)(g0 + GPT * tid) * 6);
        float4 f0 = wp[0], f1 = wp[1], f2 = wp[2], f3 = wp[3], f4 = wp[4], f5 = wp[5];
        float w[24] = {f0.x,f0.y,f0.z,f0.w, f1.x,f1.y,f1.z,f1.w,
                       f2.x,f2.y,f2.z,f2.w, f3.x,f3.y,f3.z,f3.w,
                       f4.x,f4.y,f4.z,f4.w, f5.x,f5.y,f5.z,f5.w};
        #pragma unroll
        for (int u = 0; u < GPT; ++u) {
            const float* ww = &w[6 * u];
            float m = fmaxf(fmaxf(fmaxf(ww[0], ww[1]), fmaxf(ww[2], ww[3])),
                            fmaxf(ww[4], ww[5]));
            float e0 = __expf(ww[0] - m), e1 = __expf(ww[1] - m),
                  e2 = __expf(ww[2] - m), e3 = __expf(ww[3] - m),
                  e4 = __expf(ww[4] - m), e5 = __expf(ww[5] - m);
            float inv = 1.0f / (e0 + e1 + e2 + e3 + e4 + e5);
            e0 *= inv; e1 *= inv; e2 *= inv; e3 *= inv; e4 *= inv; e5 *= inv;
            // out0 linear coefs
            cw[u][0] = e0 + e1; cw[u][1] = e2 + e3; cw[u][2] = e4 + e5;
            // out1 linear coefs
            dl[u][0] = e3 + e5; dl[u][1] = e1 + e4; dl[u][2] = e0 + e2;
            // quadratic coefs (out1 adds qq, out2 subtracts; out2 = s - o0 - o1)
            qc[u][0] = e0 - e1 + e2 - e3;
            qc[u][1] = e1 - e0 + e4 - e5;
            qc[u][2] = e3 - e2 + e5 - e4;
        }
    }

    // ---- stage x[b0..b0+RT-1, (base .. base+SEG-1) % DIN] into LDS ----
    // wrap point (DIN - base) is a multiple of 4, so no float4 crosses it.
    for (int k = tid; k < RT * SEG4; k += 256) {
        int r  = k / SEG4;
        int j  = (k - r * SEG4) * 4;
        int gi = base + j;
        if (gi >= DIN) gi -= DIN;
        *reinterpret_cast<float4*>(&sx[r][j]) =
            *reinterpret_cast<const float4*>(x + (size_t)(b0 + r) * DIN + gi);
    }
    __syncthreads();

    // ---- compute: thread t owns gates g0+4t .. g0+4t+3 ----
    const int jb = 12 * tid;
    #pragma unroll
    for (int r = 0; r < RT; ++r) {
        const float4* sp = reinterpret_cast<const float4*>(&sx[r][jb]);
        float4 f0 = sp[0], f1 = sp[1], f2 = sp[2], f3 = sp[3];
        // gate u reads floats jb + 3u+1 .. jb + 3u+3
        float a[GPT][3] = { {f0.y, f0.z, f0.w},
                            {f1.x, f1.y, f1.z},
                            {f1.w, f2.x, f2.y},
                            {f2.z, f2.w, f3.x} };
        float o[12];
        #pragma unroll
        for (int u = 0; u < GPT; ++u) {
            float a0 = a[u][0], a1 = a[u][1], a2 = a[u][2];
            float p01 = a0 * a1, p02 = a0 * a2, p12 = a1 * a2;
            float o0 = cw[u][0] * a0 + cw[u][1] * a1 + cw[u][2] * a2;
            float qq = qc[u][0] * p01 + qc[u][1] * p02 + qc[u][2] * p12;
            float o1 = dl[u][0] * a0 + dl[u][1] * a1 + dl[u][2] * a2 + qq;
            float o2 = (a0 + a1 + a2) - o0 - o1;
            o[3*u + 0] = o0; o[3*u + 1] = o1; o[3*u + 2] = o2;
        }
        float* op = out + (size_t)(b0 + r) * (3 * NG) + base + jb;
        float4* op4 = reinterpret_cast<float4*>(op);
        op4[0] = make_float4(o[0], o[1], o[2],  o[3]);
        op4[1] = make_float4(o[4], o[5], o[6],  o[7]);
        op4[2] = make_float4(o[8], o[9], o[10], o[11]);
    }
}

extern "C" void kernel_launch(void* const* d_in, const int* in_sizes, int n_in,
                              void* d_out, int out_size, void* d_ws, size_t ws_size,
                              hipStream_t stream) {
    const float* x    = (const float*)d_in[0];   // (4096, 4096) f32
    const float* wgts = (const float*)d_in[1];   // (2048, 6)   f32
    // d_in[2] = connections — deterministic (3g+1+k) % DIN, not needed.
    float* out = (float*)d_out;                  // (4096, 6144) f32

    const int grid = 2 * (4096 / RT);            // 2 gate tiles x 1024 row tiles
    fredkin_kernel<<<grid, 256, 0, stream>>>(x, wgts, out);
}

// Round 5
// 50.037 us; speedup vs baseline: 1.0923x; 1.0923x over previous
//
#include <hip/hip_runtime.h>

// Fredkin6Layer, algebraically reduced to 9 coefs/gate:
//   a = x[b, (3g+1..3g+3) & 4095],  w = softmax(wgts[g])
//   o0 = (w0+w1)a0 + (w2+w3)a1 + (w4+w5)a2
//   o1 = (w3+w5)a0 + (w1+w4)a1 + (w0+w2)a2
//        + (w0-w1+w2-w3)a0a1 + (w1-w0+w4-w5)a0a2 + (w3-w2+w5-w4)a1a2
//   o2 = (a0+a1+a2) - o0 - o1
// No LDS, no barriers: per-wave register-pipelined streaming.

constexpr int DIN  = 4096;
constexpr int NG   = 2048;
constexpr int DOUT = 3 * NG;   // 6144
constexpr int GPB  = 1024;     // gates per block tile
constexpr int GPT  = 4;        // gates per thread
constexpr int RPB  = 4;        // rows per block

__global__ __launch_bounds__(256, 5) void fredkin_kernel(
    const float* __restrict__ x,
    const float* __restrict__ wgts,
    float* __restrict__ out)
{
    const int tid = threadIdx.x;
    const int gt  = blockIdx.x >> 10;        // gate tile in HIGH bits: row-pair
    const int rb  = blockIdx.x & 1023;       //   blocks land on same XCD (1024%8==0)
    const int g0  = gt * GPB;
    const int base = 3 * g0;                 // 0 or 3072
    const int r0  = rb * RPB;

    // ---- per-thread coefficients for its 4 gates (softmax in registers) ----
    float cw[GPT][3], dl[GPT][3], qc[GPT][3];
    {
        const float4* wp =
            reinterpret_cast<const float4*>(wgts + (size_t)(g0 + GPT * tid) * 6);
        float4 f0 = wp[0], f1 = wp[1], f2 = wp[2], f3 = wp[3], f4 = wp[4], f5 = wp[5];
        float w[24] = {f0.x,f0.y,f0.z,f0.w, f1.x,f1.y,f1.z,f1.w,
                       f2.x,f2.y,f2.z,f2.w, f3.x,f3.y,f3.z,f3.w,
                       f4.x,f4.y,f4.z,f4.w, f5.x,f5.y,f5.z,f5.w};
        #pragma unroll
        for (int u = 0; u < GPT; ++u) {
            const float* ww = &w[6 * u];
            float m = fmaxf(fmaxf(fmaxf(ww[0], ww[1]), fmaxf(ww[2], ww[3])),
                            fmaxf(ww[4], ww[5]));
            float e0 = __expf(ww[0] - m), e1 = __expf(ww[1] - m),
                  e2 = __expf(ww[2] - m), e3 = __expf(ww[3] - m),
                  e4 = __expf(ww[4] - m), e5 = __expf(ww[5] - m);
            float inv = 1.0f / (e0 + e1 + e2 + e3 + e4 + e5);
            e0 *= inv; e1 *= inv; e2 *= inv; e3 *= inv; e4 *= inv; e5 *= inv;
            cw[u][0] = e0 + e1; cw[u][1] = e2 + e3; cw[u][2] = e4 + e5;
            dl[u][0] = e3 + e5; dl[u][1] = e1 + e4; dl[u][2] = e0 + e2;
            qc[u][0] = e0 - e1 + e2 - e3;
            qc[u][1] = e1 - e0 + e4 - e5;
            qc[u][2] = e3 - e2 + e5 - e4;
        }
    }

    // ---- per-thread input window: 4 aligned float4 at cols (base+12t+4k)&4095 ----
    const int jb = 12 * tid;
    const float4* xp0; const float4* xp1; const float4* xp2; const float4* xp3;
    {
        int c0 = (base + jb +  0) & (DIN - 1);
        int c1 = (base + jb +  4) & (DIN - 1);
        int c2 = (base + jb +  8) & (DIN - 1);
        int c3 = (base + jb + 12) & (DIN - 1);
        xp0 = reinterpret_cast<const float4*>(x + c0);
        xp1 = reinterpret_cast<const float4*>(x + c1);
        xp2 = reinterpret_cast<const float4*>(x + c2);
        xp3 = reinterpret_cast<const float4*>(x + c3);
    }
    const size_t rs4 = DIN / 4;               // float4 per x row

    size_t ro = (size_t)r0 * rs4;
    float4 f0 = xp0[ro], f1 = xp1[ro], f2 = xp2[ro], f3 = xp3[ro];

    float* op = out + (size_t)r0 * DOUT + base + jb;

    #pragma unroll
    for (int r = 0; r < RPB; ++r) {
        float4 g0v, g1v, g2v, g3v;
        if (r + 1 < RPB) {                     // prefetch next row (stays in flight
            size_t rn = ro + rs4;              //  while we compute this one)
            g0v = xp0[rn]; g1v = xp1[rn]; g2v = xp2[rn]; g3v = xp3[rn];
        }

        float a[GPT][3] = { {f0.y, f0.z, f0.w},
                            {f1.x, f1.y, f1.z},
                            {f1.w, f2.x, f2.y},
                            {f2.z, f2.w, f3.x} };
        float o[12];
        #pragma unroll
        for (int u = 0; u < GPT; ++u) {
            float a0 = a[u][0], a1 = a[u][1], a2 = a[u][2];
            float p01 = a0 * a1, p02 = a0 * a2, p12 = a1 * a2;
            float t0 = cw[u][0] * a0 + cw[u][1] * a1 + cw[u][2] * a2;
            float qq = qc[u][0] * p01 + qc[u][1] * p02 + qc[u][2] * p12;
            float t1 = dl[u][0] * a0 + dl[u][1] * a1 + dl[u][2] * a2 + qq;
            float t2 = (a0 + a1 + a2) - t0 - t1;
            o[3*u + 0] = t0; o[3*u + 1] = t1; o[3*u + 2] = t2;
        }
        float4* op4 = reinterpret_cast<float4*>(op);
        op4[0] = make_float4(o[0], o[1], o[2],  o[3]);
        op4[1] = make_float4(o[4], o[5], o[6],  o[7]);
        op4[2] = make_float4(o[8], o[9], o[10], o[11]);

        if (r + 1 < RPB) {
            f0 = g0v; f1 = g1v; f2 = g2v; f3 = g3v;
            ro += rs4;
            op += DOUT;
        }
    }
}

extern "C" void kernel_launch(void* const* d_in, const int* in_sizes, int n_in,
                              void* d_out, int out_size, void* d_ws, size_t ws_size,
                              hipStream_t stream) {
    const float* x    = (const float*)d_in[0];   // (4096, 4096) f32
    const float* wgts = (const float*)d_in[1];   // (2048, 6)   f32
    // d_in[2] = connections — deterministic (3g+1+k) % DIN, not needed.
    float* out = (float*)d_out;                  // (4096, 6144) f32

    const int grid = 2 * (4096 / RPB);           // gt in high bit: 2 x 1024 blocks
    fredkin_kernel<<<grid, 256, 0, stream>>>(x, wgts, out);
}